// Round 3
// baseline (1027.134 us; speedup 1.0000x reference)
//
#include <hip/hip_runtime.h>

#define EPSF     1e-8f
#define LAMBF    0.5f
#define L2NORMF  1e-4f
#define NUSERS   100000
#define NITEMS   50000
#define EMB      64
#define RREL     3
#define NNZ_     1000000
#define IGNNZ    500000
#define BB       512
#define KK       100

#define NB       (4 * NITEMS)            // 4 concatenated histogram segments
#define CHUNK    512
#define NCHUNK   ((NB + CHUNK - 1) / CHUNK)   // 391
#define TOTE     (3 * IGNNZ + NNZ_)      // 2.5M bucket entries

// user -> batch slot map
__global__ void scatter_user(const int* __restrict__ user, int* __restrict__ slot) {
    int b = blockIdx.x * blockDim.x + threadIdx.x;
    if (b < BB) slot[user[b]] = b;
}

// histogram of keys into hist (pre-zeroed segment)
__global__ void hist_k(const int* __restrict__ keys, int n, int* __restrict__ hist) {
    int i = blockIdx.x * blockDim.x + threadIdx.x;
    int stride = gridDim.x * blockDim.x;
    for (; i < n; i += stride) atomicAdd(&hist[keys[i]], 1);
}

// ---- 3-phase exclusive scan over hist[NB] ----
__global__ void scan_chunksum(const int* __restrict__ hist, int* __restrict__ csum) {
    int b = blockIdx.x, t = threadIdx.x;               // 512 threads
    int i = b * CHUNK + t;
    int v = (i < NB) ? hist[i] : 0;
    for (int off = 32; off > 0; off >>= 1) v += __shfl_xor(v, off);
    __shared__ int wsum[8];
    if ((t & 63) == 0) wsum[t >> 6] = v;
    __syncthreads();
    if (t == 0) {
        int s = 0;
        for (int w = 0; w < 8; w++) s += wsum[w];
        csum[b] = s;
    }
}

__global__ void scan_offsets(const int* __restrict__ csum, int* __restrict__ coff) {
    __shared__ int s[CHUNK];
    int t = threadIdx.x;
    int v = (t < NCHUNK) ? csum[t] : 0;
    s[t] = v;
    __syncthreads();
    for (int d = 1; d < CHUNK; d <<= 1) {
        int x = (t >= d) ? s[t - d] : 0;
        __syncthreads();
        s[t] += x;
        __syncthreads();
    }
    if (t < NCHUNK) coff[t] = s[t] - v;   // exclusive
}

__global__ void scan_final(const int* __restrict__ hist, const int* __restrict__ coff,
                           int* __restrict__ offsets, int* __restrict__ pos) {
    int b = blockIdx.x, t = threadIdx.x;
    int i = b * CHUNK + t;
    __shared__ int s[CHUNK];
    int v = (i < NB) ? hist[i] : 0;
    s[t] = v;
    __syncthreads();
    for (int d = 1; d < CHUNK; d <<= 1) {
        int x = (t >= d) ? s[t - d] : 0;
        __syncthreads();
        s[t] += x;
        __syncthreads();
    }
    int excl = s[t] - v + coff[b];
    if (i < NB) { offsets[i] = excl; pos[i] = excl; }
    if (i == NB - 1) offsets[NB] = TOTE;
}

// scatter edge payloads into buckets; payload==null -> store edge index
__global__ void bucket_fill(const int* __restrict__ keys, const int* __restrict__ payload,
                            int n, int* __restrict__ pos_seg, int* __restrict__ bucket) {
    int i = blockIdx.x * blockDim.x + threadIdx.x;
    int stride = gridDim.x * blockDim.x;
    for (; i < n; i += stride) {
        int slot = atomicAdd(&pos_seg[keys[i]], 1);
        bucket[slot] = payload ? payload[i] : i;
    }
}

// pull-gather item_agg row, normalize by deg, fuse @Wp -> item_prop2
__global__ void ig_gather_prop(const int* __restrict__ cols, const float* __restrict__ vals,
                               const float* __restrict__ item_emb, const int* __restrict__ offs,
                               const int* __restrict__ bucket, const float* __restrict__ Wp,
                               float* __restrict__ prop2) {
    int t = threadIdx.x, w = t >> 6, lane = t & 63;
    int r = blockIdx.x * 4 + w;                        // 12500 blocks x 4 waves = 50000
    int start = offs[r], end = offs[r + 1];
    float acc = 0.f, deg = 0.f;
    for (int k = start; k < end; k++) {
        int e = bucket[k];
        int c = cols[e];
        float v = vals[e];
        acc += v * item_emb[c * 64 + lane];
        deg += v;
    }
    __shared__ float rowb[4][64];
    rowb[w][lane] = acc / (deg + EPSF);
    __syncthreads();
    float o = 0.f;
#pragma unroll
    for (int k2 = 0; k2 < 64; k2++) o += rowb[w][k2] * Wp[k2 * 64 + lane];
    prop2[r * 64 + lane] = o;
}

// pull-gather item_feature row (bucket holds user rows directly), fuse @W -> itf2
__global__ void train_gather_W(const float* __restrict__ user_emb, const int* __restrict__ offs,
                               const int* __restrict__ bucket, const float* __restrict__ Wm,
                               float* __restrict__ itf2) {
    int t = threadIdx.x, w = t >> 6, lane = t & 63;
    int r = blockIdx.x * 4 + w;
    int start = offs[r], end = offs[r + 1];
    float acc = 0.f;
    for (int k = start; k < end; k++) {
        int u = bucket[k];
        acc += user_emb[u * 64 + lane];
    }
    __shared__ float rowb[4][64];
    rowb[w][lane] = acc;
    __syncthreads();
    float o = 0.f;
#pragma unroll
    for (int k2 = 0; k2 < 64; k2++) o += rowb[w][k2] * Wm[k2 * 64 + lane];
    itf2[r * 64 + lane] = o;
}

// filtered relation scan: only edges whose user is in the batch (tiny atomic volume)
__global__ void rel_scan(const int* __restrict__ rows, const int* __restrict__ cols,
                         const int* __restrict__ slot, const float* __restrict__ item_emb,
                         const float* __restrict__ item_prop2,
                         float* __restrict__ acc_neigh, float* __restrict__ acc_prop,
                         float* __restrict__ ubc) {
    int lane = threadIdx.x & 63;
    int wave = (blockIdx.x * blockDim.x + threadIdx.x) >> 6;
    int nwaves = (gridDim.x * blockDim.x) >> 6;
    for (int base = wave * 64; base < NNZ_; base += nwaves * 64) {
        int e = base + lane;
        int s = -1, c = 0;
        if (e < NNZ_) {
            s = slot[rows[e]];
            c = cols[e];
        }
        unsigned long long mask = __ballot(s >= 0);
        while (mask) {
            int j = __builtin_ctzll(mask);
            mask &= mask - 1;
            int bs = __shfl(s, j);
            int bc = __shfl(c, j);
            atomicAdd(&acc_neigh[bs * EMB + lane], item_emb[bc * EMB + lane]);
            atomicAdd(&acc_prop[bs * EMB + lane], item_prop2[bc * EMB + lane]);
            if (lane == 0) atomicAdd(&ubc[bs], 1.0f);
        }
    }
}

// per batch row: proj = tmp_user_item_p[user[b]] @ Wb, then
// score2[b,k] += dot(proj, [item_emb[it] | item_prop2[it]])
__global__ void proj_score2(const int* __restrict__ user, const int* __restrict__ slot,
                            const float* __restrict__ ubc, const float* __restrict__ acc_neigh,
                            const float* __restrict__ acc_prop, const float* __restrict__ Wb,
                            const int* __restrict__ item, const float* __restrict__ item_emb,
                            const float* __restrict__ item_prop2, float* __restrict__ score2) {
    int b = blockIdx.x;
    int tid = threadIdx.x;               // 256
    __shared__ float tbuf[128];
    __shared__ float p[128];
    int rep = slot[user[b]];
    float inv = 1.0f / (ubc[rep] + EPSF);
    if (tid < 64)       tbuf[tid] = acc_neigh[rep * 64 + tid] * inv;
    else if (tid < 128) tbuf[tid] = acc_prop[rep * 64 + (tid - 64)] * inv;
    __syncthreads();
    if (tid < 128) {
        float o = 0.f;
#pragma unroll 8
        for (int k = 0; k < 128; k++) o += tbuf[k] * Wb[k * 128 + tid];
        p[tid] = o;
    }
    __syncthreads();
    int wave = tid >> 6, lane = tid & 63;
    for (int k = wave; k < KK; k += 4) {
        int it = item[b * KK + k];
        float s = p[lane] * item_emb[it * 64 + lane] + p[64 + lane] * item_prop2[it * 64 + lane];
        for (int off = 32; off > 0; off >>= 1) s += __shfl_xor(s, off);
        if (lane == 0) score2[b * KK + k] += s;
    }
}

// final: ufeat + @W in-block, then score1 + LAMB*score2/R + l2
__global__ void final_k(const int* __restrict__ user, const int* __restrict__ item,
                        const int* __restrict__ slot, const float* __restrict__ ubc,
                        const float* __restrict__ acc_neigh, const float* __restrict__ mw,
                        const float* __restrict__ W, const float* __restrict__ user_emb,
                        const float* __restrict__ item_emb, const float* __restrict__ itf2,
                        const float* __restrict__ score2, float* __restrict__ out,
                        float* __restrict__ l2out) {
    int b = blockIdx.x;
    int tid = threadIdx.x;               // 256
    int wave = tid >> 6, lane = tid & 63;
    __shared__ float uf[64], u1[64], u2[64];
    __shared__ float red[4];
    int u = user[b];
    if (tid < 64) {
        int rep = slot[u];
        float w0 = mw[0], w1 = mw[1], w2 = mw[2];
        float c0 = ubc[0 * BB + rep], c1 = ubc[1 * BB + rep], c2 = ubc[2 * BB + rep];
        float invT = 1.0f / (c0 * w0 + c1 * w1 + c2 * w2 + EPSF);
        float f = (c0 * w0 * invT) / (c0 + EPSF) * acc_neigh[(0 * BB + rep) * 64 + tid]
                + (c1 * w1 * invT) / (c1 + EPSF) * acc_neigh[(1 * BB + rep) * 64 + tid]
                + (c2 * w2 * invT) / (c2 + EPSF) * acc_neigh[(2 * BB + rep) * 64 + tid];
        uf[tid] = f;
        u1[tid] = user_emb[u * 64 + tid];
    }
    __syncthreads();
    if (tid < 64) {
        float o = 0.f;
#pragma unroll
        for (int k = 0; k < 64; k++) o += uf[k] * W[k * 64 + tid];
        u2[tid] = o;
    }
    __syncthreads();
    float l2part = 0.f;
    for (int k = wave; k < KK; k += 4) {
        int it = item[b * KK + k];
        float e1 = item_emb[it * 64 + lane], e2 = itf2[it * 64 + lane];
        float s = u1[lane] * e1 + u2[lane] * e2;
        float q = e1 * e1 + e2 * e2;
        for (int off = 32; off > 0; off >>= 1) {
            s += __shfl_xor(s, off);
            q += __shfl_xor(q, off);
        }
        if (lane == 0) {
            out[b * KK + k] = s + LAMBF * (score2[b * KK + k] * (1.0f / (float)RREL));
            l2part += q;
        }
    }
    float su = u1[lane] * u1[lane] + u2[lane] * u2[lane];
    for (int off = 32; off > 0; off >>= 1) su += __shfl_xor(su, off);
    if (wave == 0 && lane == 0) l2part += (float)KK * su;
    if (lane == 0) red[wave] = l2part;
    __syncthreads();
    if (tid == 0) atomicAdd(l2out, L2NORMF * (red[0] + red[1] + red[2] + red[3]));
}

extern "C" void kernel_launch(void* const* d_in, const int* in_sizes, int n_in,
                              void* d_out, int out_size, void* d_ws, size_t ws_size,
                              hipStream_t stream) {
    const int*   user       = (const int*)d_in[0];
    const int*   item       = (const int*)d_in[1];
    const int*   rel_rows   = (const int*)d_in[2];
    const int*   rel_cols   = (const int*)d_in[3];
    const int*   ig_rows    = (const int*)d_in[4];
    const int*   ig_cols    = (const int*)d_in[5];
    const float* ig_vals    = (const float*)d_in[6];
    const int*   train_rows = (const int*)d_in[7];
    const int*   train_cols = (const int*)d_in[8];
    const float* user_emb   = (const float*)d_in[9];
    const float* item_emb   = (const float*)d_in[10];
    const float* mw         = (const float*)d_in[11];
    const float* Wb         = (const float*)d_in[12];  // R x 128 x 128
    const float* Wp         = (const float*)d_in[13];  // R x 64 x 64
    const float* W          = (const float*)d_in[14];  // 64 x 64
    float* out = (float*)d_out;

    // ---- workspace layout (4-byte words) ----
    float* ws = (float*)d_ws;
    size_t o = 0;
    int*   user_slot  = (int*)(ws + o); o += NUSERS;
    float* item_prop2 = ws + o; o += (size_t)NITEMS * 64;   // reused as itf2 at the end
    int*   hist       = (int*)(ws + o); o += NB;
    int*   offsets    = (int*)(ws + o); o += NB + 1;
    int*   pos        = (int*)(ws + o); o += NB;
    int*   csum       = (int*)(ws + o); o += NCHUNK;
    int*   coff       = (int*)(ws + o); o += NCHUNK;
    int*   bucket     = (int*)(ws + o); o += TOTE;
    // contiguous zero zone:
    float* acc_neigh  = ws + o; o += (size_t)RREL * BB * 64;
    float* acc_prop   = ws + o; o += (size_t)RREL * BB * 64;
    float* ubc        = ws + o; o += (size_t)RREL * BB;
    float* score2     = ws + o; o += (size_t)BB * KK;
    if (ws_size < o * sizeof(float)) return;   // undersized scratch: bail cleanly

    size_t zero_zone = (size_t)RREL * BB * 64 * 2 + RREL * BB + BB * KK;

    // phase 0: init
    hipMemsetAsync(user_slot, 0xFF, (size_t)NUSERS * 4, stream);          // = -1
    scatter_user<<<2, 256, 0, stream>>>(user, user_slot);
    hipMemsetAsync(hist, 0, (size_t)NB * 4, stream);
    hipMemsetAsync(acc_neigh, 0, zero_zone * 4, stream);
    hipMemsetAsync(out + (out_size - 1), 0, 4, stream);                   // l2 slot

    // phase 1: build CSR buckets for the 3 ig graphs (key=ig_rows) + train (key=train_cols)
    for (int i = 0; i < RREL; i++)
        hist_k<<<2048, 256, 0, stream>>>(ig_rows + (size_t)i * IGNNZ, IGNNZ, hist + i * NITEMS);
    hist_k<<<2048, 256, 0, stream>>>(train_cols, NNZ_, hist + 3 * NITEMS);
    scan_chunksum<<<NCHUNK, CHUNK, 0, stream>>>(hist, csum);
    scan_offsets<<<1, CHUNK, 0, stream>>>(csum, coff);
    scan_final<<<NCHUNK, CHUNK, 0, stream>>>(hist, coff, offsets, pos);
    for (int i = 0; i < RREL; i++)
        bucket_fill<<<2048, 256, 0, stream>>>(ig_rows + (size_t)i * IGNNZ, nullptr, IGNNZ,
                                              pos + i * NITEMS, bucket);
    bucket_fill<<<2048, 256, 0, stream>>>(train_cols, train_rows, NNZ_,
                                          pos + 3 * NITEMS, bucket);

    // phase 2: per relation
    for (int i = 0; i < RREL; i++) {
        ig_gather_prop<<<NITEMS / 4, 256, 0, stream>>>(ig_cols + (size_t)i * IGNNZ,
                                                       ig_vals + (size_t)i * IGNNZ,
                                                       item_emb, offsets + i * NITEMS, bucket,
                                                       Wp + (size_t)i * 64 * 64, item_prop2);
        rel_scan<<<2048, 256, 0, stream>>>(rel_rows + (size_t)i * NNZ_, rel_cols + (size_t)i * NNZ_,
                                           user_slot, item_emb, item_prop2,
                                           acc_neigh + (size_t)i * BB * 64,
                                           acc_prop + (size_t)i * BB * 64, ubc + (size_t)i * BB);
        proj_score2<<<BB, 256, 0, stream>>>(user, user_slot, ubc + (size_t)i * BB,
                                            acc_neigh + (size_t)i * BB * 64,
                                            acc_prop + (size_t)i * BB * 64,
                                            Wb + (size_t)i * 128 * 128,
                                            item, item_emb, item_prop2, score2);
    }

    // phase 3: item_feature via pull-gather, fused @W (itf2 reuses prop2 buffer)
    float* itf2 = item_prop2;
    train_gather_W<<<NITEMS / 4, 256, 0, stream>>>(user_emb, offsets + 3 * NITEMS, bucket, W, itf2);
    final_k<<<BB, 256, 0, stream>>>(user, item, user_slot, ubc, acc_neigh, mw, W,
                                    user_emb, item_emb, itf2, score2,
                                    out, out + (out_size - 1));
}

// Round 4
// 906.813 us; speedup vs baseline: 1.1327x; 1.1327x over previous
//
#include <hip/hip_runtime.h>

#define EPSF     1e-8f
#define LAMBF    0.5f
#define L2NORMF  1e-4f
#define NUSERS   100000
#define NITEMS   50000
#define EMB      64
#define RREL     3
#define NNZ_     1000000
#define IGNNZ    500000
#define BB       512
#define KK       100

#define NB       (4 * NITEMS)                 // 4 concatenated histogram segments
#define CHUNK    512
#define NCHUNK   ((NB + CHUNK - 1) / CHUNK)   // 391
#define IGTOT    (RREL * IGNNZ)               // 1.5M
#define TOTE     (IGTOT + NNZ_)               // 2.5M bucket entries

// user -> batch slot map + batch-item flags
__global__ void scatter_maps(const int* __restrict__ user, const int* __restrict__ item,
                             int* __restrict__ slot, int* __restrict__ iflag) {
    int i = blockIdx.x * blockDim.x + threadIdx.x;
    if (i < BB) slot[user[i]] = i;
    if (i < BB * KK) iflag[item[i]] = 1;
}

// unified histogram over 4 segments: 3 ig graphs (key=ig_rows) + train (key=train_cols)
__global__ void hist_all(const int* __restrict__ ig_rows, const int* __restrict__ train_cols,
                         int* __restrict__ hist) {
    int i = blockIdx.x * blockDim.x + threadIdx.x;
    int stride = gridDim.x * blockDim.x;
    for (; i < TOTE; i += stride) {
        if (i < IGTOT) atomicAdd(&hist[(i / IGNNZ) * NITEMS + ig_rows[i]], 1);
        else           atomicAdd(&hist[3 * NITEMS + train_cols[i - IGTOT]], 1);
    }
}

// ---- 3-phase exclusive scan over hist[NB] ----
__global__ void scan_chunksum(const int* __restrict__ hist, int* __restrict__ csum) {
    int b = blockIdx.x, t = threadIdx.x;               // 512 threads
    int i = b * CHUNK + t;
    int v = (i < NB) ? hist[i] : 0;
    for (int off = 32; off > 0; off >>= 1) v += __shfl_xor(v, off);
    __shared__ int wsum[8];
    if ((t & 63) == 0) wsum[t >> 6] = v;
    __syncthreads();
    if (t == 0) {
        int s = 0;
        for (int w = 0; w < 8; w++) s += wsum[w];
        csum[b] = s;
    }
}

__global__ void scan_offsets(const int* __restrict__ csum, int* __restrict__ coff) {
    __shared__ int s[CHUNK];
    int t = threadIdx.x;
    int v = (t < NCHUNK) ? csum[t] : 0;
    s[t] = v;
    __syncthreads();
    for (int d = 1; d < CHUNK; d <<= 1) {
        int x = (t >= d) ? s[t - d] : 0;
        __syncthreads();
        s[t] += x;
        __syncthreads();
    }
    if (t < NCHUNK) coff[t] = s[t] - v;   // exclusive
}

__global__ void scan_final(const int* __restrict__ hist, const int* __restrict__ coff,
                           int* __restrict__ offsets, int* __restrict__ pos) {
    int b = blockIdx.x, t = threadIdx.x;
    int i = b * CHUNK + t;
    __shared__ int s[CHUNK];
    int v = (i < NB) ? hist[i] : 0;
    s[t] = v;
    __syncthreads();
    for (int d = 1; d < CHUNK; d <<= 1) {
        int x = (t >= d) ? s[t - d] : 0;
        __syncthreads();
        s[t] += x;
        __syncthreads();
    }
    int excl = s[t] - v + coff[b];
    if (i < NB) { offsets[i] = excl; pos[i] = excl; }
    if (i == NB - 1) offsets[NB] = TOTE;
}

// unified bucket fill: ig segs store flat edge index; train seg stores user row
__global__ void fill_all(const int* __restrict__ ig_rows, const int* __restrict__ train_rows,
                         const int* __restrict__ train_cols, int* __restrict__ pos,
                         int* __restrict__ bucket) {
    int i = blockIdx.x * blockDim.x + threadIdx.x;
    int stride = gridDim.x * blockDim.x;
    for (; i < TOTE; i += stride) {
        if (i < IGTOT) {
            int s = atomicAdd(&pos[(i / IGNNZ) * NITEMS + ig_rows[i]], 1);
            bucket[s] = i;
        } else {
            int e = i - IGTOT;
            int s = atomicAdd(&pos[3 * NITEMS + train_cols[e]], 1);
            bucket[s] = train_rows[e];
        }
    }
}

// pull-gather item_agg row (8-deep MLP), normalize by deg, fuse @Wp -> prop2
__global__ void ig_gather_prop(const int* __restrict__ cols, const float* __restrict__ vals,
                               const float* __restrict__ item_emb, const int* __restrict__ offs,
                               const int* __restrict__ bucket, const float* __restrict__ Wp,
                               float* __restrict__ prop2) {
    int t = threadIdx.x, w = t >> 6, lane = t & 63;
    int r = blockIdx.x * 4 + w;                        // 12500 blocks x 4 waves
    int k = offs[r], end = offs[r + 1];
    float acc = 0.f, deg = 0.f;
    for (; k + 8 <= end; k += 8) {
        int e0 = bucket[k + 0], e1 = bucket[k + 1], e2 = bucket[k + 2], e3 = bucket[k + 3];
        int e4 = bucket[k + 4], e5 = bucket[k + 5], e6 = bucket[k + 6], e7 = bucket[k + 7];
        int c0 = cols[e0], c1 = cols[e1], c2 = cols[e2], c3 = cols[e3];
        int c4 = cols[e4], c5 = cols[e5], c6 = cols[e6], c7 = cols[e7];
        float v0 = vals[e0], v1 = vals[e1], v2 = vals[e2], v3 = vals[e3];
        float v4 = vals[e4], v5 = vals[e5], v6 = vals[e6], v7 = vals[e7];
        float f0 = item_emb[c0 * 64 + lane], f1 = item_emb[c1 * 64 + lane];
        float f2 = item_emb[c2 * 64 + lane], f3 = item_emb[c3 * 64 + lane];
        float f4 = item_emb[c4 * 64 + lane], f5 = item_emb[c5 * 64 + lane];
        float f6 = item_emb[c6 * 64 + lane], f7 = item_emb[c7 * 64 + lane];
        acc += v0 * f0 + v1 * f1 + v2 * f2 + v3 * f3 + v4 * f4 + v5 * f5 + v6 * f6 + v7 * f7;
        deg += v0 + v1 + v2 + v3 + v4 + v5 + v6 + v7;
    }
    for (; k < end; k++) {
        int e = bucket[k];
        float v = vals[e];
        acc += v * item_emb[cols[e] * 64 + lane];
        deg += v;
    }
    __shared__ float rowb[4][64];
    rowb[w][lane] = acc / (deg + EPSF);
    __syncthreads();
    float o = 0.f;
#pragma unroll
    for (int k2 = 0; k2 < 64; k2++) o += rowb[w][k2] * Wp[k2 * 64 + lane];
    prop2[r * 64 + lane] = o;
}

// pull-gather item_feature row (8-deep MLP, batch-flagged rows only), fuse @W -> itf2
__global__ void train_gather_W(const float* __restrict__ user_emb, const int* __restrict__ offs,
                               const int* __restrict__ bucket, const int* __restrict__ iflag,
                               const float* __restrict__ Wm, float* __restrict__ itf2) {
    int t = threadIdx.x, w = t >> 6, lane = t & 63;
    int r = blockIdx.x * 4 + w;
    int active = iflag[r];
    float acc = 0.f;
    if (active) {
        int k = offs[r], end = offs[r + 1];
        for (; k + 8 <= end; k += 8) {
            int u0 = bucket[k + 0], u1 = bucket[k + 1], u2 = bucket[k + 2], u3 = bucket[k + 3];
            int u4 = bucket[k + 4], u5 = bucket[k + 5], u6 = bucket[k + 6], u7 = bucket[k + 7];
            float f0 = user_emb[u0 * 64 + lane], f1 = user_emb[u1 * 64 + lane];
            float f2 = user_emb[u2 * 64 + lane], f3 = user_emb[u3 * 64 + lane];
            float f4 = user_emb[u4 * 64 + lane], f5 = user_emb[u5 * 64 + lane];
            float f6 = user_emb[u6 * 64 + lane], f7 = user_emb[u7 * 64 + lane];
            acc += ((f0 + f1) + (f2 + f3)) + ((f4 + f5) + (f6 + f7));
        }
        for (; k < end; k++) acc += user_emb[bucket[k] * 64 + lane];
    }
    __shared__ float rowb[4][64];
    rowb[w][lane] = acc;
    __syncthreads();
    if (active) {
        float o = 0.f;
#pragma unroll
        for (int k2 = 0; k2 < 64; k2++) o += rowb[w][k2] * Wm[k2 * 64 + lane];
        itf2[r * 64 + lane] = o;
    }
}

// filtered relation scan: only edges whose user is in the batch contribute
__global__ void rel_scan(const int* __restrict__ rows, const int* __restrict__ cols,
                         const int* __restrict__ slot, const float* __restrict__ item_emb,
                         const float* __restrict__ item_prop2,
                         float* __restrict__ acc_neigh, float* __restrict__ acc_prop,
                         float* __restrict__ ubc) {
    int lane = threadIdx.x & 63;
    int wave = (blockIdx.x * blockDim.x + threadIdx.x) >> 6;
    int nwaves = (gridDim.x * blockDim.x) >> 6;
    for (int base = wave * 64; base < NNZ_; base += nwaves * 64) {
        int e = base + lane;
        int s = -1, c = 0;
        if (e < NNZ_) {
            s = slot[rows[e]];
            c = cols[e];
        }
        unsigned long long mask = __ballot(s >= 0);
        while (mask) {
            int j = __builtin_ctzll(mask);
            mask &= mask - 1;
            int bs = __shfl(s, j);
            int bc = __shfl(c, j);
            atomicAdd(&acc_neigh[bs * EMB + lane], item_emb[bc * EMB + lane]);
            atomicAdd(&acc_prop[bs * EMB + lane], item_prop2[bc * EMB + lane]);
            if (lane == 0) atomicAdd(&ubc[bs], 1.0f);
        }
    }
}

// per batch row: proj = tmp_user_item_p[user[b]] @ Wb, then
// score2[b,k] += dot(proj, [item_emb[it] | item_prop2[it]])
__global__ void proj_score2(const int* __restrict__ user, const int* __restrict__ slot,
                            const float* __restrict__ ubc, const float* __restrict__ acc_neigh,
                            const float* __restrict__ acc_prop, const float* __restrict__ Wb,
                            const int* __restrict__ item, const float* __restrict__ item_emb,
                            const float* __restrict__ item_prop2, float* __restrict__ score2) {
    int b = blockIdx.x;
    int tid = threadIdx.x;               // 256
    __shared__ float tbuf[128];
    __shared__ float p[128];
    int rep = slot[user[b]];
    float inv = 1.0f / (ubc[rep] + EPSF);
    if (tid < 64)       tbuf[tid] = acc_neigh[rep * 64 + tid] * inv;
    else if (tid < 128) tbuf[tid] = acc_prop[rep * 64 + (tid - 64)] * inv;
    __syncthreads();
    if (tid < 128) {
        float o = 0.f;
#pragma unroll 8
        for (int k = 0; k < 128; k++) o += tbuf[k] * Wb[k * 128 + tid];
        p[tid] = o;
    }
    __syncthreads();
    int wave = tid >> 6, lane = tid & 63;
    for (int k = wave; k < KK; k += 4) {
        int it = item[b * KK + k];
        float s = p[lane] * item_emb[it * 64 + lane] + p[64 + lane] * item_prop2[it * 64 + lane];
        for (int off = 32; off > 0; off >>= 1) s += __shfl_xor(s, off);
        if (lane == 0) score2[b * KK + k] += s;
    }
}

// final: ufeat + @W in-block, then score1 + LAMB*score2/R + l2
__global__ void final_k(const int* __restrict__ user, const int* __restrict__ item,
                        const int* __restrict__ slot, const float* __restrict__ ubc,
                        const float* __restrict__ acc_neigh, const float* __restrict__ mw,
                        const float* __restrict__ W, const float* __restrict__ user_emb,
                        const float* __restrict__ item_emb, const float* __restrict__ itf2,
                        const float* __restrict__ score2, float* __restrict__ out,
                        float* __restrict__ l2out) {
    int b = blockIdx.x;
    int tid = threadIdx.x;               // 256
    int wave = tid >> 6, lane = tid & 63;
    __shared__ float uf[64], u1[64], u2[64];
    __shared__ float red[4];
    int u = user[b];
    if (tid < 64) {
        int rep = slot[u];
        float w0 = mw[0], w1 = mw[1], w2 = mw[2];
        float c0 = ubc[0 * BB + rep], c1 = ubc[1 * BB + rep], c2 = ubc[2 * BB + rep];
        float invT = 1.0f / (c0 * w0 + c1 * w1 + c2 * w2 + EPSF);
        float f = (c0 * w0 * invT) / (c0 + EPSF) * acc_neigh[(0 * BB + rep) * 64 + tid]
                + (c1 * w1 * invT) / (c1 + EPSF) * acc_neigh[(1 * BB + rep) * 64 + tid]
                + (c2 * w2 * invT) / (c2 + EPSF) * acc_neigh[(2 * BB + rep) * 64 + tid];
        uf[tid] = f;
        u1[tid] = user_emb[u * 64 + tid];
    }
    __syncthreads();
    if (tid < 64) {
        float o = 0.f;
#pragma unroll
        for (int k = 0; k < 64; k++) o += uf[k] * W[k * 64 + tid];
        u2[tid] = o;
    }
    __syncthreads();
    float l2part = 0.f;
    for (int k = wave; k < KK; k += 4) {
        int it = item[b * KK + k];
        float e1 = item_emb[it * 64 + lane], e2 = itf2[it * 64 + lane];
        float s = u1[lane] * e1 + u2[lane] * e2;
        float q = e1 * e1 + e2 * e2;
        for (int off = 32; off > 0; off >>= 1) {
            s += __shfl_xor(s, off);
            q += __shfl_xor(q, off);
        }
        if (lane == 0) {
            out[b * KK + k] = s + LAMBF * (score2[b * KK + k] * (1.0f / (float)RREL));
            l2part += q;
        }
    }
    float su = u1[lane] * u1[lane] + u2[lane] * u2[lane];
    for (int off = 32; off > 0; off >>= 1) su += __shfl_xor(su, off);
    if (wave == 0 && lane == 0) l2part += (float)KK * su;
    if (lane == 0) red[wave] = l2part;
    __syncthreads();
    if (tid == 0) atomicAdd(l2out, L2NORMF * (red[0] + red[1] + red[2] + red[3]));
}

extern "C" void kernel_launch(void* const* d_in, const int* in_sizes, int n_in,
                              void* d_out, int out_size, void* d_ws, size_t ws_size,
                              hipStream_t stream) {
    const int*   user       = (const int*)d_in[0];
    const int*   item       = (const int*)d_in[1];
    const int*   rel_rows   = (const int*)d_in[2];
    const int*   rel_cols   = (const int*)d_in[3];
    const int*   ig_rows    = (const int*)d_in[4];
    const int*   ig_cols    = (const int*)d_in[5];
    const float* ig_vals    = (const float*)d_in[6];
    const int*   train_rows = (const int*)d_in[7];
    const int*   train_cols = (const int*)d_in[8];
    const float* user_emb   = (const float*)d_in[9];
    const float* item_emb   = (const float*)d_in[10];
    const float* mw         = (const float*)d_in[11];
    const float* Wb         = (const float*)d_in[12];  // R x 128 x 128
    const float* Wp         = (const float*)d_in[13];  // R x 64 x 64
    const float* W          = (const float*)d_in[14];  // 64 x 64
    float* out = (float*)d_out;

    // ---- workspace layout (4-byte words) ----
    float* ws = (float*)d_ws;
    size_t o = 0;
    int*   user_slot  = (int*)(ws + o); o += NUSERS;          // memset 0xFF
    int*   hist       = (int*)(ws + o); o += NB;              // memset 0 (with iflag)
    int*   iflag      = (int*)(ws + o); o += NITEMS;
    int*   offsets    = (int*)(ws + o); o += NB + 1;
    int*   pos        = (int*)(ws + o); o += NB;
    int*   csum       = (int*)(ws + o); o += NCHUNK;
    int*   coff       = (int*)(ws + o); o += NCHUNK;
    float* item_prop2 = ws + o; o += (size_t)NITEMS * 64;     // reused as itf2 at the end
    int*   bucket     = (int*)(ws + o); o += TOTE;
    // contiguous zero zone:
    float* acc_neigh  = ws + o; o += (size_t)RREL * BB * 64;
    float* acc_prop   = ws + o; o += (size_t)RREL * BB * 64;
    float* ubc        = ws + o; o += (size_t)RREL * BB;
    float* score2     = ws + o; o += (size_t)BB * KK;
    if (ws_size < o * sizeof(float)) return;   // undersized scratch: bail cleanly

    size_t zero_zone = (size_t)RREL * BB * 64 * 2 + RREL * BB + BB * KK;

    // phase 0: init
    hipMemsetAsync(user_slot, 0xFF, (size_t)NUSERS * 4, stream);          // = -1
    hipMemsetAsync(hist, 0, (size_t)(NB + NITEMS) * 4, stream);           // hist + iflag
    hipMemsetAsync(acc_neigh, 0, zero_zone * 4, stream);
    hipMemsetAsync(out + (out_size - 1), 0, 4, stream);                   // l2 slot
    scatter_maps<<<(BB * KK + 255) / 256, 256, 0, stream>>>(user, item, user_slot, iflag);

    // phase 1: CSR build (single hist + single fill over the 2.5M-entry space)
    hist_all<<<4096, 256, 0, stream>>>(ig_rows, train_cols, hist);
    scan_chunksum<<<NCHUNK, CHUNK, 0, stream>>>(hist, csum);
    scan_offsets<<<1, CHUNK, 0, stream>>>(csum, coff);
    scan_final<<<NCHUNK, CHUNK, 0, stream>>>(hist, coff, offsets, pos);
    fill_all<<<4096, 256, 0, stream>>>(ig_rows, train_rows, train_cols, pos, bucket);

    // phase 2: per relation
    for (int i = 0; i < RREL; i++) {
        ig_gather_prop<<<NITEMS / 4, 256, 0, stream>>>(ig_cols, ig_vals, item_emb,
                                                       offsets + i * NITEMS, bucket,
                                                       Wp + (size_t)i * 64 * 64, item_prop2);
        rel_scan<<<2048, 256, 0, stream>>>(rel_rows + (size_t)i * NNZ_, rel_cols + (size_t)i * NNZ_,
                                           user_slot, item_emb, item_prop2,
                                           acc_neigh + (size_t)i * BB * 64,
                                           acc_prop + (size_t)i * BB * 64, ubc + (size_t)i * BB);
        proj_score2<<<BB, 256, 0, stream>>>(user, user_slot, ubc + (size_t)i * BB,
                                            acc_neigh + (size_t)i * BB * 64,
                                            acc_prop + (size_t)i * BB * 64,
                                            Wb + (size_t)i * 128 * 128,
                                            item, item_emb, item_prop2, score2);
    }

    // phase 3: item_feature via flagged pull-gather, fused @W (itf2 reuses prop2 buffer)
    float* itf2 = item_prop2;
    train_gather_W<<<NITEMS / 4, 256, 0, stream>>>(user_emb, offsets + 3 * NITEMS, bucket,
                                                   iflag, W, itf2);
    final_k<<<BB, 256, 0, stream>>>(user, item, user_slot, ubc, acc_neigh, mw, W,
                                    user_emb, item_emb, itf2, score2,
                                    out, out + (out_size - 1));
}